// Round 2
// baseline (28.368 us; speedup 1.0000x reference)
//
#include <hip/hip_runtime.h>
#include <math.h>

// AttController: two cascaded PIDs (angle -> rate) + inertia coupling.
// 4 elements per thread; all global accesses are aligned float4 (16B/lane).
// Inputs (setup_inputs order), all float32:
//   0: ref_rpy      (N,3)
//   1: meas_rpy     (N,3)
//   2: meas_omegab  (N,3)
//   3: J            (N,3,3)
//   4: integ        (6,N)   rows 0..2 angle, 3..5 rate
//   5: prev_err     (6,N)   rows 0..2 unused (angle kd=0)
//   6: d_filt       (6,N)   rows 0..2 unused (angle tau=0 -> alpha=1, kd=0)
// Output: tau (N,3) float32.

#define PI_F 3.14159265358979323846f
#define TWO_PI_F 6.28318530717958647692f

__device__ __forceinline__ void pid_and_tau(
    const float err0, const float err1, const float err2,
    const float w0, const float w1, const float w2,
    const float ig_a0, const float ig_a1, const float ig_a2,
    const float ig_r0, const float ig_r1, const float ig_r2,
    const float pe0, const float pe1, const float pe2,
    const float df0, const float df1, const float df2,
    const float* Jm,   // 9 floats, row-major
    float& o0, float& o1, float& o2)
{
    // angle PID (tau=0 -> alpha=1; kd=0 -> no D term)
    const float DT_A = 0.01f;
    float u0 = 6.0f * err0 + 1.0f * (ig_a0 + err0 * DT_A);
    float u1 = 6.0f * err1 + 1.0f * (ig_a1 + err1 * DT_A);
    float u2 = 3.0f * err2 + 0.5f * (ig_a2 + err2 * DT_A);
    u0 = fminf(fmaxf(u0, -10.0f), 10.0f);
    u1 = fminf(fmaxf(u1, -10.0f), 10.0f);
    u2 = fminf(fmaxf(u2, -5.0f), 5.0f);

    // rate PID
    const float DT_R = 0.002f;
    const float ALPHA_R = DT_R / (0.005f + DT_R);  // 2/7 in f32
    float e0 = u0 - w0, e1 = u1 - w1, e2 = u2 - w2;
    float dn0 = df0 + ALPHA_R * ((e0 - pe0) / DT_R - df0);
    float dn1 = df1 + ALPHA_R * ((e1 - pe1) / DT_R - df1);
    float dn2 = df2 + ALPHA_R * ((e2 - pe2) / DT_R - df2);
    float a0 = 0.25f * e0 + 0.5f * (ig_r0 + e0 * DT_R) + 0.0025f * dn0;
    float a1 = 0.25f * e1 + 0.5f * (ig_r1 + e1 * DT_R) + 0.0025f * dn1;
    float a2 = 0.12f * e2 + 0.1f * (ig_r2 + e2 * DT_R) + 0.0f * dn2;
    a0 = fminf(fmaxf(a0, -1.0f), 1.0f);
    a1 = fminf(fmaxf(a1, -1.0f), 1.0f);
    a2 = fminf(fmaxf(a2, -0.5f), 0.5f);

    // tau = J*alpha + w x (J*w)
    float Jw0 = Jm[0]*w0 + Jm[1]*w1 + Jm[2]*w2;
    float Jw1 = Jm[3]*w0 + Jm[4]*w1 + Jm[5]*w2;
    float Jw2 = Jm[6]*w0 + Jm[7]*w1 + Jm[8]*w2;
    float Ja0 = Jm[0]*a0 + Jm[1]*a1 + Jm[2]*a2;
    float Ja1 = Jm[3]*a0 + Jm[4]*a1 + Jm[5]*a2;
    float Ja2 = Jm[6]*a0 + Jm[7]*a1 + Jm[8]*a2;
    o0 = Ja0 + (w1 * Jw2 - w2 * Jw1);
    o1 = Ja1 + (w2 * Jw0 - w0 * Jw2);
    o2 = Ja2 + (w0 * Jw1 - w1 * Jw0);
}

__device__ __forceinline__ float wrap_yaw(float e) {
    if (e >  PI_F) e -= TWO_PI_F;
    if (e < -PI_F) e += TWO_PI_F;
    return e;
}

__global__ __launch_bounds__(256) void att_ctrl_v4(
    const float* __restrict__ ref_rpy,
    const float* __restrict__ meas_rpy,
    const float* __restrict__ meas_omegab,
    const float* __restrict__ J,
    const float* __restrict__ integ,
    const float* __restrict__ prev_err,
    const float* __restrict__ d_filt,
    float* __restrict__ out,
    int n)
{
    const int t = blockIdx.x * blockDim.x + threadIdx.x;
    const long long base = 4LL * t;
    if (base >= n) return;

    if (base + 4 <= n) {
        // ---- fully vectorized fast path: 30 float4 loads, 3 float4 stores ----
        float r[12], m[12], w[12], Jm[36], o[12];
        float iga[12], igr[12], pe[12], df[12];

        #pragma unroll
        for (int q = 0; q < 3; ++q) {
            *(float4*)&r[4*q] = *(const float4*)(ref_rpy     + 3*base + 4*q);
            *(float4*)&m[4*q] = *(const float4*)(meas_rpy    + 3*base + 4*q);
            *(float4*)&w[4*q] = *(const float4*)(meas_omegab + 3*base + 4*q);
        }
        #pragma unroll
        for (int q = 0; q < 9; ++q)
            *(float4*)&Jm[4*q] = *(const float4*)(J + 9*base + 4*q);
        #pragma unroll
        for (int k = 0; k < 3; ++k) {
            *(float4*)&iga[4*k] = *(const float4*)(integ    + (size_t)k       * n + base);
            *(float4*)&igr[4*k] = *(const float4*)(integ    + (size_t)(k + 3) * n + base);
            *(float4*)&pe[4*k]  = *(const float4*)(prev_err + (size_t)(k + 3) * n + base);
            *(float4*)&df[4*k]  = *(const float4*)(d_filt   + (size_t)(k + 3) * n + base);
        }

        #pragma unroll
        for (int j = 0; j < 4; ++j) {
            float e0 = r[3*j+0] - m[3*j+0];
            float e1 = r[3*j+1] - m[3*j+1];
            float e2 = wrap_yaw(r[3*j+2] - m[3*j+2]);
            pid_and_tau(e0, e1, e2,
                        w[3*j+0], w[3*j+1], w[3*j+2],
                        iga[0*4+j], iga[1*4+j], iga[2*4+j],
                        igr[0*4+j], igr[1*4+j], igr[2*4+j],
                        pe[0*4+j], pe[1*4+j], pe[2*4+j],
                        df[0*4+j], df[1*4+j], df[2*4+j],
                        &Jm[9*j],
                        o[3*j+0], o[3*j+1], o[3*j+2]);
        }

        #pragma unroll
        for (int q = 0; q < 3; ++q)
            *(float4*)(out + 3*base + 4*q) = *(const float4*)&o[4*q];
    } else {
        // ---- scalar tail (n not divisible by 4) ----
        for (long long i = base; i < n; ++i) {
            float e0 = ref_rpy[3*i+0] - meas_rpy[3*i+0];
            float e1 = ref_rpy[3*i+1] - meas_rpy[3*i+1];
            float e2 = wrap_yaw(ref_rpy[3*i+2] - meas_rpy[3*i+2]);
            float w0 = meas_omegab[3*i+0], w1 = meas_omegab[3*i+1], w2 = meas_omegab[3*i+2];
            float Jm[9];
            #pragma unroll
            for (int q = 0; q < 9; ++q) Jm[q] = J[9*i+q];
            float o0, o1, o2;
            pid_and_tau(e0, e1, e2, w0, w1, w2,
                        integ[0*(size_t)n+i], integ[1*(size_t)n+i], integ[2*(size_t)n+i],
                        integ[3*(size_t)n+i], integ[4*(size_t)n+i], integ[5*(size_t)n+i],
                        prev_err[3*(size_t)n+i], prev_err[4*(size_t)n+i], prev_err[5*(size_t)n+i],
                        d_filt[3*(size_t)n+i], d_filt[4*(size_t)n+i], d_filt[5*(size_t)n+i],
                        Jm, o0, o1, o2);
            out[3*i+0] = o0; out[3*i+1] = o1; out[3*i+2] = o2;
        }
    }
}

extern "C" void kernel_launch(void* const* d_in, const int* in_sizes, int n_in,
                              void* d_out, int out_size, void* d_ws, size_t ws_size,
                              hipStream_t stream) {
    const float* ref_rpy     = (const float*)d_in[0];
    const float* meas_rpy    = (const float*)d_in[1];
    const float* meas_omegab = (const float*)d_in[2];
    const float* J           = (const float*)d_in[3];
    const float* integ       = (const float*)d_in[4];
    const float* prev_err    = (const float*)d_in[5];
    const float* d_filt      = (const float*)d_in[6];
    float* out = (float*)d_out;

    int n = in_sizes[0] / 3;            // ref_rpy is (N,3)
    int nthreads = (n + 3) / 4;         // 4 elements per thread
    int block = 256;
    int grid = (nthreads + block - 1) / block;
    att_ctrl_v4<<<grid, block, 0, stream>>>(
        ref_rpy, meas_rpy, meas_omegab, J, integ, prev_err, d_filt, out, n);
}

// Round 3
// 24.704 us; speedup vs baseline: 1.1483x; 1.1483x over previous
//
#include <hip/hip_runtime.h>
#include <math.h>

// AttController: two cascaded PIDs (angle -> rate) + inertia coupling.
// 2 elements per thread; all global accesses are aligned 8B (dwordx2).
// Inputs (setup_inputs order), all float32:
//   0: ref_rpy      (N,3)
//   1: meas_rpy     (N,3)
//   2: meas_omegab  (N,3)
//   3: J            (N,3,3)
//   4: integ        (6,N)   rows 0..2 angle, 3..5 rate
//   5: prev_err     (6,N)   rows 0..2 unused (angle kd=0)
//   6: d_filt       (6,N)   rows 0..2 unused (angle tau=0 -> alpha=1, kd=0)
// Output: tau (N,3) float32 (nontemporal stores: keep L3 for inputs).

typedef float v2f __attribute__((ext_vector_type(2)));

#define PI_F 3.14159265358979323846f
#define TWO_PI_F 6.28318530717958647692f

__device__ __forceinline__ float wrap_yaw(float e) {
    if (e >  PI_F) e -= TWO_PI_F;
    if (e < -PI_F) e += TWO_PI_F;
    return e;
}

__device__ __forceinline__ void pid_and_tau(
    const float err0, const float err1, const float err2,
    const float w0, const float w1, const float w2,
    const float ig_a0, const float ig_a1, const float ig_a2,
    const float ig_r0, const float ig_r1, const float ig_r2,
    const float pe0, const float pe1, const float pe2,
    const float df0, const float df1, const float df2,
    const float* Jm,   // 9 floats, row-major
    float& o0, float& o1, float& o2)
{
    // angle PID (tau=0 -> alpha=1; kd=0 -> no D term)
    const float DT_A = 0.01f;
    float u0 = 6.0f * err0 + 1.0f * (ig_a0 + err0 * DT_A);
    float u1 = 6.0f * err1 + 1.0f * (ig_a1 + err1 * DT_A);
    float u2 = 3.0f * err2 + 0.5f * (ig_a2 + err2 * DT_A);
    u0 = fminf(fmaxf(u0, -10.0f), 10.0f);
    u1 = fminf(fmaxf(u1, -10.0f), 10.0f);
    u2 = fminf(fmaxf(u2, -5.0f), 5.0f);

    // rate PID
    const float DT_R = 0.002f;
    const float ALPHA_R = DT_R / (0.005f + DT_R);  // 2/7 in f32
    float e0 = u0 - w0, e1 = u1 - w1, e2 = u2 - w2;
    float dn0 = df0 + ALPHA_R * ((e0 - pe0) / DT_R - df0);
    float dn1 = df1 + ALPHA_R * ((e1 - pe1) / DT_R - df1);
    float dn2 = df2 + ALPHA_R * ((e2 - pe2) / DT_R - df2);
    float a0 = 0.25f * e0 + 0.5f * (ig_r0 + e0 * DT_R) + 0.0025f * dn0;
    float a1 = 0.25f * e1 + 0.5f * (ig_r1 + e1 * DT_R) + 0.0025f * dn1;
    float a2 = 0.12f * e2 + 0.1f * (ig_r2 + e2 * DT_R) + 0.0f * dn2;
    a0 = fminf(fmaxf(a0, -1.0f), 1.0f);
    a1 = fminf(fmaxf(a1, -1.0f), 1.0f);
    a2 = fminf(fmaxf(a2, -0.5f), 0.5f);

    // tau = J*alpha + w x (J*w)
    float Jw0 = Jm[0]*w0 + Jm[1]*w1 + Jm[2]*w2;
    float Jw1 = Jm[3]*w0 + Jm[4]*w1 + Jm[5]*w2;
    float Jw2 = Jm[6]*w0 + Jm[7]*w1 + Jm[8]*w2;
    float Ja0 = Jm[0]*a0 + Jm[1]*a1 + Jm[2]*a2;
    float Ja1 = Jm[3]*a0 + Jm[4]*a1 + Jm[5]*a2;
    float Ja2 = Jm[6]*a0 + Jm[7]*a1 + Jm[8]*a2;
    o0 = Ja0 + (w1 * Jw2 - w2 * Jw1);
    o1 = Ja1 + (w2 * Jw0 - w0 * Jw2);
    o2 = Ja2 + (w0 * Jw1 - w1 * Jw0);
}

__global__ __launch_bounds__(128) void att_ctrl_v2e(
    const float* __restrict__ ref_rpy,
    const float* __restrict__ meas_rpy,
    const float* __restrict__ meas_omegab,
    const float* __restrict__ J,
    const float* __restrict__ integ,
    const float* __restrict__ prev_err,
    const float* __restrict__ d_filt,
    float* __restrict__ out,
    int n)
{
    const int t = blockIdx.x * blockDim.x + threadIdx.x;
    const long long base = 2LL * t;
    if (base >= n) return;

    if (base + 2 <= n) {
        // ---- 2-element fast path: all loads/stores are 8B-aligned dwordx2 ----
        float r[6], m[6], w[6], Jm[18], o[6];
        float iga[6], igr[6], pe[6], df[6];

        #pragma unroll
        for (int q = 0; q < 3; ++q) {
            *(v2f*)&r[2*q] = *(const v2f*)(ref_rpy     + 6LL*t + 2*q);
            *(v2f*)&m[2*q] = *(const v2f*)(meas_rpy    + 6LL*t + 2*q);
            *(v2f*)&w[2*q] = *(const v2f*)(meas_omegab + 6LL*t + 2*q);
        }
        #pragma unroll
        for (int q = 0; q < 9; ++q)
            *(v2f*)&Jm[2*q] = *(const v2f*)(J + 18LL*t + 2*q);
        #pragma unroll
        for (int k = 0; k < 3; ++k) {
            *(v2f*)&iga[2*k] = *(const v2f*)(integ    + (size_t)k       * n + base);
            *(v2f*)&igr[2*k] = *(const v2f*)(integ    + (size_t)(k + 3) * n + base);
            *(v2f*)&pe[2*k]  = *(const v2f*)(prev_err + (size_t)(k + 3) * n + base);
            *(v2f*)&df[2*k]  = *(const v2f*)(d_filt   + (size_t)(k + 3) * n + base);
        }

        #pragma unroll
        for (int j = 0; j < 2; ++j) {
            float e0 = r[3*j+0] - m[3*j+0];
            float e1 = r[3*j+1] - m[3*j+1];
            float e2 = wrap_yaw(r[3*j+2] - m[3*j+2]);
            pid_and_tau(e0, e1, e2,
                        w[3*j+0], w[3*j+1], w[3*j+2],
                        iga[0*2+j], iga[1*2+j], iga[2*2+j],
                        igr[0*2+j], igr[1*2+j], igr[2*2+j],
                        pe[0*2+j], pe[1*2+j], pe[2*2+j],
                        df[0*2+j], df[1*2+j], df[2*2+j],
                        &Jm[9*j],
                        o[3*j+0], o[3*j+1], o[3*j+2]);
        }

        #pragma unroll
        for (int q = 0; q < 3; ++q) {
            v2f v = *(const v2f*)&o[2*q];
            __builtin_nontemporal_store(v, (v2f*)(out + 6LL*t + 2*q));
        }
    } else {
        // ---- scalar tail (n odd) ----
        const long long i = base;
        float e0 = ref_rpy[3*i+0] - meas_rpy[3*i+0];
        float e1 = ref_rpy[3*i+1] - meas_rpy[3*i+1];
        float e2 = wrap_yaw(ref_rpy[3*i+2] - meas_rpy[3*i+2]);
        float w0 = meas_omegab[3*i+0], w1 = meas_omegab[3*i+1], w2 = meas_omegab[3*i+2];
        float Jm[9];
        #pragma unroll
        for (int q = 0; q < 9; ++q) Jm[q] = J[9*i+q];
        float o0, o1, o2;
        pid_and_tau(e0, e1, e2, w0, w1, w2,
                    integ[0*(size_t)n+i], integ[1*(size_t)n+i], integ[2*(size_t)n+i],
                    integ[3*(size_t)n+i], integ[4*(size_t)n+i], integ[5*(size_t)n+i],
                    prev_err[3*(size_t)n+i], prev_err[4*(size_t)n+i], prev_err[5*(size_t)n+i],
                    d_filt[3*(size_t)n+i], d_filt[4*(size_t)n+i], d_filt[5*(size_t)n+i],
                    Jm, o0, o1, o2);
        out[3*i+0] = o0; out[3*i+1] = o1; out[3*i+2] = o2;
    }
}

extern "C" void kernel_launch(void* const* d_in, const int* in_sizes, int n_in,
                              void* d_out, int out_size, void* d_ws, size_t ws_size,
                              hipStream_t stream) {
    const float* ref_rpy     = (const float*)d_in[0];
    const float* meas_rpy    = (const float*)d_in[1];
    const float* meas_omegab = (const float*)d_in[2];
    const float* J           = (const float*)d_in[3];
    const float* integ       = (const float*)d_in[4];
    const float* prev_err    = (const float*)d_in[5];
    const float* d_filt      = (const float*)d_in[6];
    float* out = (float*)d_out;

    int n = in_sizes[0] / 3;            // ref_rpy is (N,3)
    int nthreads = (n + 1) / 2;         // 2 elements per thread
    int block = 128;                    // keep grid large: ~30 waves/CU available
    int grid = (nthreads + block - 1) / block;
    att_ctrl_v2e<<<grid, block, 0, stream>>>(
        ref_rpy, meas_rpy, meas_omegab, J, integ, prev_err, d_filt, out, n);
}